// Round 10
// baseline (1785.141 us; speedup 1.0000x reference)
//
#include <hip/hip_runtime.h>
#include <math.h>

#define B_ 8
#define N_ 4096

// ---------------------------------------------------------------- utilities

__global__ void zero_kernel(float* p, int n) {
    int i = blockIdx.x * 256 + threadIdx.x;
    if (i < n) p[i] = 0.0f;
}

// dst[i*CO + o] = src[o*sstride + coff + i]
__global__ void transpose_kernel(const float* __restrict__ src, float* __restrict__ dst,
                                 int CO, int CI, int sstride, int coff) {
    int idx = blockIdx.x * 256 + threadIdx.x;
    if (idx >= CO * CI) return;
    int i = idx / CO, o = idx - i * CO;
    dst[idx] = src[o * sstride + coff + i];
}

// wtpre[c*256+o] : o<128 -> wf1[o][c] (center), o>=128 -> wf1[o-128][32+c] (knn)
__global__ void prep_pre_kernel(const float* __restrict__ wf1, const float* __restrict__ bf1,
                                float* __restrict__ wtpre, float* __restrict__ bpre) {
    int idx = blockIdx.x * 256 + threadIdx.x;
    if (idx < 8192) {
        int c = idx >> 8, o = idx & 255;
        wtpre[idx] = (o < 128) ? wf1[o * 64 + c] : wf1[(o - 128) * 64 + 32 + c];
    }
    int j = idx - 8192;
    if (j >= 0 && j < 256) bpre[j] = (j < 128) ? bf1[j] : 0.0f;
}

template<int C>
__global__ void sq_kernel(const float* __restrict__ F, float* __restrict__ SQ) {
    int idx = blockIdx.x * 256 + threadIdx.x;
    const float* p = F + (size_t)idx * C;
    float s = 0.0f;
    #pragma unroll
    for (int c = 0; c < C; ++c) s = fmaf(p[c], p[c], s);
    SQ[idx] = s;
}

// ---------------------------------------------------------------- knn (top-16 nearest)
// Hot loop: branchless bitonic top-k on FLOAT keys + int index payload. Block-end /
// inter-half merges use the exact u64 (ord<<32 | 4095-col) format.

__device__ __forceinline__ void cas_asc(unsigned long long& x, unsigned long long& y) {
    unsigned long long a = x, b = y;
    bool sw = a > b;
    x = sw ? b : a;
    y = sw ? a : b;
}

// k, o both asc-sorted; k <- top-16 of (k U o), asc-sorted
__device__ __forceinline__ void merge_top(unsigned long long (&k)[16],
                                          const unsigned long long (&o)[16]) {
    #pragma unroll
    for (int i = 0; i < 16; ++i) {
        unsigned long long bb = o[15 - i];
        if (bb > k[i]) k[i] = bb;         // k now bitonic, holds top-16 multiset
    }
    #pragma unroll
    for (int st = 8; st >= 1; st >>= 1)   // bitonic clean -> asc
        #pragma unroll
        for (int i = 0; i < 16; ++i)
            if ((i & st) == 0) cas_asc(k[i], k[i + st]);
}

__device__ __forceinline__ void casf(float& x, float& y, int& xi, int& yi) {
    bool sw = x > y;
    float a = sw ? y : x;  float b = sw ? x : y;
    int ai = sw ? yi : xi; int bi = sw ? xi : yi;
    x = a; y = b; xi = ai; yi = bi;
}

// full bitonic sort, ascending by value
__device__ __forceinline__ void sort16f(float (&v)[16], int (&ix)[16]) {
    #pragma unroll
    for (int sz = 2; sz <= 16; sz <<= 1)
        #pragma unroll
        for (int st = sz >> 1; st >= 1; st >>= 1)
            #pragma unroll
            for (int i = 0; i < 16; ++i)
                if ((i & st) == 0) {
                    if ((i & sz) == 0) casf(v[i], v[i + st], ix[i], ix[i + st]);
                    else                casf(v[i + st], v[i], ix[i + st], ix[i]);
                }
}

// kv/ki asc-sorted running top-16; nv/ni asc-sorted candidates
__device__ __forceinline__ void merge_topf(float (&kv)[16], int (&ki)[16],
                                           const float (&nv)[16], const int (&ni)[16]) {
    #pragma unroll
    for (int i = 0; i < 16; ++i) {
        bool tk = nv[15 - i] > kv[i];
        kv[i] = tk ? nv[15 - i] : kv[i];
        ki[i] = tk ? ni[15 - i] : ki[i];
    }
    #pragma unroll
    for (int st = 8; st >= 1; st >>= 1)
        #pragma unroll
        for (int i = 0; i < 16; ++i)
            if ((i & st) == 0) casf(kv[i], kv[i + st], ki[i], ki[i + st]);
}

template<int C>
__global__ __launch_bounds__(256, 3) void knn_kernel(
    const float* __restrict__ F, const float* __restrict__ SQ,
    unsigned long long* __restrict__ Kout) {
    // phase1 overlay: Rf[C*68] | Cf[C*68] | Ds[64*72]; phase2 overlay: QL[64*65] (u64)
    constexpr int P1F = 2 * C * 68 + 64 * 72;                       // floats
    constexpr int P1W = (P1F + 1) / 2;                              // u64 words
    constexpr int SMW = (P1W > 64 * 65) ? P1W : 64 * 65;
    __shared__ __align__(16) unsigned long long SM[SMW];
    __shared__ float sqr[64];
    __shared__ float sqc[64];
    float* Rf = (float*)SM;
    float* Cf = Rf + C * 68;
    float* Ds = Cf + C * 68;                                        // stride 72
    const int t = threadIdx.x;
    const int b = blockIdx.y;
    const int r0 = blockIdx.x * 64;
    const int half = blockIdx.z;
    const int H0 = half * 2048;
    const int rt = (t & 15) * 4, ct = (t >> 4) * 4;                 // gemm tile
    const int sr = t & 63, sq = t >> 6;                             // selection row/quarter

    if constexpr (C % 4 == 0) {
        for (int idx = t; idx < 64 * (C / 4); idx += 256) {
            int rr = idx / (C / 4), c4 = (idx - rr * (C / 4)) * 4;
            const float4 v = *(const float4*)&F[((size_t)b * N_ + r0 + rr) * C + c4];
            Rf[(c4 + 0) * 68 + rr] = v.x; Rf[(c4 + 1) * 68 + rr] = v.y;
            Rf[(c4 + 2) * 68 + rr] = v.z; Rf[(c4 + 3) * 68 + rr] = v.w;
        }
    } else {
        for (int idx = t; idx < 64 * C; idx += 256) {
            int rr = idx / C, c = idx - rr * C;
            Rf[c * 68 + rr] = F[((size_t)b * N_ + r0 + rr) * C + c];
        }
    }
    if (t < 64) sqr[t] = SQ[(size_t)b * N_ + r0 + t];

    float kv[16]; int ki[16];
    #pragma unroll
    for (int j = 0; j < 16; ++j) { kv[j] = -3.4e38f; ki[j] = 0; }

    for (int c0 = H0; c0 < H0 + 2048; c0 += 64) {
        if constexpr (C % 4 == 0) {
            for (int idx = t; idx < 64 * (C / 4); idx += 256) {
                int cc = idx / (C / 4), c4 = (idx - cc * (C / 4)) * 4;
                const float4 v = *(const float4*)&F[((size_t)b * N_ + c0 + cc) * C + c4];
                Cf[(c4 + 0) * 68 + cc] = v.x; Cf[(c4 + 1) * 68 + cc] = v.y;
                Cf[(c4 + 2) * 68 + cc] = v.z; Cf[(c4 + 3) * 68 + cc] = v.w;
            }
        } else {
            for (int idx = t; idx < 64 * C; idx += 256) {
                int cc = idx / C, c = idx - cc * C;
                Cf[c * 68 + cc] = F[((size_t)b * N_ + c0 + cc) * C + c];
            }
        }
        if (t < 64) sqc[t] = SQ[(size_t)b * N_ + c0 + t];
        __syncthreads();                          // staging ready; prev rescans done

        float acc[4][4];
        #pragma unroll
        for (int ii = 0; ii < 4; ++ii)
            #pragma unroll
            for (int jj = 0; jj < 4; ++jj) acc[ii][jj] = 0.0f;
        #pragma unroll
        for (int i = 0; i < C; ++i) {
            float a4[4], w4[4];
            *(float4*)a4 = *(const float4*)&Rf[i * 68 + rt];
            *(float4*)w4 = *(const float4*)&Cf[i * 68 + ct];
            #pragma unroll
            for (int ii = 0; ii < 4; ++ii)
                #pragma unroll
                for (int jj = 0; jj < 4; ++jj)
                    acc[ii][jj] = fmaf(a4[ii], w4[jj], acc[ii][jj]);
        }
        #pragma unroll
        for (int ii = 0; ii < 4; ++ii) {
            float e[4];
            #pragma unroll
            for (int jj = 0; jj < 4; ++jj)
                e[jj] = 2.0f * acc[ii][jj] - sqr[rt + ii] - sqc[ct + jj];
            *(float2*)&Ds[(rt + ii) * 72 + ct] = make_float2(e[0], e[1]);
            *(float2*)&Ds[(rt + ii) * 72 + ct + 2] = make_float2(e[2], e[3]);
        }
        __syncthreads();                          // Ds ready

        // rescan own 16 values, float-key bitonic update
        float nv[16]; int ni[16];
        *(float4*)&nv[0]  = *(const float4*)&Ds[sr * 72 + sq * 16 + 0];
        *(float4*)&nv[4]  = *(const float4*)&Ds[sr * 72 + sq * 16 + 4];
        *(float4*)&nv[8]  = *(const float4*)&Ds[sr * 72 + sq * 16 + 8];
        *(float4*)&nv[12] = *(const float4*)&Ds[sr * 72 + sq * 16 + 12];
        #pragma unroll
        for (int s = 0; s < 16; ++s) ni[s] = c0 + sq * 16 + s;
        sort16f(nv, ni);
        merge_topf(kv, ki, nv, ni);
    }
    __syncthreads();                              // all rescans done before overlay reuse
    // pack to exact-order u64 keys for the merge phases
    unsigned long long kl[16];
    #pragma unroll
    for (int j = 0; j < 16; ++j) {
        unsigned int u = __float_as_uint(kv[j]);
        unsigned int ou = (u & 0x80000000u) ? ~u : (u | 0x80000000u);
        kl[j] = ((unsigned long long)ou << 32) | (unsigned int)(4095 - ki[j]);
    }
    unsigned long long* QL = SM;
    #pragma unroll
    for (int j = 0; j < 16; ++j) QL[sr * 65 + sq * 16 + j] = kl[j];
    __syncthreads();
    if (t < 64) {
        unsigned long long K[16], Tt[16];
        #pragma unroll
        for (int j = 0; j < 16; ++j) K[j] = QL[t * 65 + j];
        #pragma unroll
        for (int q = 1; q < 4; ++q) {
            #pragma unroll
            for (int j = 0; j < 16; ++j) Tt[j] = QL[t * 65 + q * 16 + j];
            merge_top(K, Tt);
        }
        size_t obase = (((size_t)b * 2 + half) * N_ + r0 + t) * 16;
        #pragma unroll
        for (int j = 0; j < 16; ++j) Kout[obase + j] = K[j];
    }
}

__global__ __launch_bounds__(256) void knn_merge_kernel(
    const unsigned long long* __restrict__ Kbuf, int* __restrict__ IDX) {
    int gid = blockIdx.x * 256 + threadIdx.x;     // 0..32767
    int b = gid >> 12, r = gid & 4095;
    unsigned long long K0[16], K1[16];
    const unsigned long long* p0 = Kbuf + (((size_t)b * 2 + 0) * N_ + r) * 16;
    const unsigned long long* p1 = Kbuf + (((size_t)b * 2 + 1) * N_ + r) * 16;
    #pragma unroll
    for (int j = 0; j < 16; ++j) { K0[j] = p0[j]; K1[j] = p1[j]; }
    merge_top(K0, K1);
    size_t ob = ((size_t)b * N_ + r) * 16;
    #pragma unroll
    for (int j = 0; j < 16; ++j)
        IDX[ob + j] = 4095 - (int)(unsigned int)(K0[15 - j] & 0xFFFFFFFFu);
}

// ---------------------------------------------------------------- edgeconv 1 (xyz, C=3 -> 32)

__global__ __launch_bounds__(256, 4) void e1_kernel(
    const float* __restrict__ xyz, const int* __restrict__ idx1,
    const float* __restrict__ wte1,
    const float* __restrict__ bg1, const float* __restrict__ bg2,
    const float* __restrict__ bf1, const float* __restrict__ bf2,
    const float* __restrict__ bf3,
    float* __restrict__ fea1) {
    __shared__ __align__(16) float Ain[10 * 132];
    __shared__ __align__(16) float Bu0[32 * 132];
    __shared__ __align__(16) float Bu1[32 * 132];
    __shared__ __align__(16) float wl[3584];
    __shared__ float bl[5][32];
    __shared__ __align__(16) float Pm1[4][8][32];
    __shared__ int idxl[128];
    const int t = threadIdx.x;
    const int b = blockIdx.x >> 9;
    const int n0 = (blockIdx.x & 511) << 3;
    const int et = (t & 31) << 2;
    const int ct = (t >> 5) << 2;

    for (int i = t; i < 3584; i += 256) wl[i] = wte1[i];
    if (t < 32) {
        bl[0][t] = bg1[t]; bl[1][t] = bg2[t]; bl[2][t] = bf1[t];
        bl[3][t] = bf2[t]; bl[4][t] = bf3[t];
    }
    if (t < 128) idxl[t] = idx1[((size_t)b * N_ + n0 + (t >> 4)) * 16 + (t & 15)];
    __syncthreads();
    if (t < 128) {
        int p = t >> 4, n = n0 + p, m = idxl[t];
        const float* xc = xyz + ((size_t)b * N_ + n) * 3;
        const float* xk = xyz + ((size_t)b * N_ + m) * 3;
        float c0 = xc[0], c1v = xc[1], c2v = xc[2];
        float k0 = xk[0], k1 = xk[1], k2 = xk[2];
        float r0 = c0 - k0, r1 = c1v - k1, r2 = c2v - k2;
        Ain[0 * 132 + t] = sqrtf(r0 * r0 + r1 * r1 + r2 * r2);
        Ain[1 * 132 + t] = c0;  Ain[2 * 132 + t] = c1v; Ain[3 * 132 + t] = c2v;
        Ain[4 * 132 + t] = k0;  Ain[5 * 132 + t] = k1;  Ain[6 * 132 + t] = k2;
        Ain[7 * 132 + t] = r0;  Ain[8 * 132 + t] = r1;  Ain[9 * 132 + t] = r2;
    }
    __syncthreads();

    float acc[4][4];
    auto gem = [&](int KK, const float* Asrc, int woff) {
        #pragma unroll
        for (int ii = 0; ii < 4; ++ii)
            #pragma unroll
            for (int jj = 0; jj < 4; ++jj) acc[ii][jj] = 0.0f;
        for (int i = 0; i < KK; ++i) {
            float a4[4], w4[4];
            *(float4*)a4 = *(const float4*)&Asrc[i * 132 + et];
            *(float4*)w4 = *(const float4*)&wl[woff + i * 32 + ct];
            #pragma unroll
            for (int ii = 0; ii < 4; ++ii)
                #pragma unroll
                for (int jj = 0; jj < 4; ++jj)
                    acc[ii][jj] = fmaf(a4[ii], w4[jj], acc[ii][jj]);
        }
    };
    auto wrout = [&](float* dst, const float* brow) {
        #pragma unroll
        for (int jj = 0; jj < 4; ++jj) {
            float tmp[4];
            #pragma unroll
            for (int ii = 0; ii < 4; ++ii) tmp[ii] = fmaxf(acc[ii][jj] + brow[ct + jj], 0.0f);
            *(float4*)&dst[(ct + jj) * 132 + et] = *(float4*)tmp;
        }
    };

    gem(10, Ain, 0);          wrout(Bu1, bl[0]);   __syncthreads();   // g1
    gem(32, Bu1, 320);                                                // g2 -> regs
    float g2r[4][4];
    #pragma unroll
    for (int ii = 0; ii < 4; ++ii)
        #pragma unroll
        for (int jj = 0; jj < 4; ++jj)
            g2r[ii][jj] = fmaxf(acc[ii][jj] + bl[1][ct + jj], 0.0f);
    gem(6, Ain + 132, 1344);  wrout(Bu0, bl[2]);   __syncthreads();   // f1
    gem(32, Bu0, 1536);       wrout(Bu1, bl[3]);   __syncthreads();   // f2
    gem(32, Bu1, 2560);                                               // f3

    float pm[4];
    #pragma unroll
    for (int jj = 0; jj < 4; ++jj) {
        float mx = 0.0f;
        #pragma unroll
        for (int ii = 0; ii < 4; ++ii) {
            float f3 = fmaxf(acc[ii][jj] + bl[4][ct + jj], 0.0f);
            mx = fmaxf(mx, g2r[ii][jj] * f3);
        }
        pm[jj] = mx;
    }
    const int sub = t & 3, pl = (t & 31) >> 2;
    *(float4*)&Pm1[sub][pl][ct] = *(float4*)pm;
    __syncthreads();
    {
        int p = t >> 5, c = t & 31;
        float v = fmaxf(fmaxf(Pm1[0][p][c], Pm1[1][p][c]), fmaxf(Pm1[2][p][c], Pm1[3][p][c]));
        fea1[((size_t)b * N_ + n0 + p) * 32 + c] = v;
    }
}

// ---------------------------------------------------------------- edgeconv 2 main (per-edge 128-wide MLPs)
// R7 configuration (measured best): 8 points / 128 edges per block, 2 blocks/CU,
// K-loop software-pipelined (next-k weight + A fragments prefetched into registers).

__global__ __launch_bounds__(256, 2) void e2_kernel(
    const float* __restrict__ xyz, const int* __restrict__ idx2,
    const float* __restrict__ CfPf,
    const float* __restrict__ wg1t, const float* __restrict__ wg2t,
    const float* __restrict__ wf2t, const float* __restrict__ wf3t,
    const float* __restrict__ bg1, const float* __restrict__ bg2,
    const float* __restrict__ bf2, const float* __restrict__ bf3,
    float* __restrict__ fea2) {
    __shared__ __align__(16) float A[128 * 128];   // 64KB, stride 128, channel-major
    __shared__ __align__(16) float G[10 * 128];    // 5KB geometry
    __shared__ float bb[4][128];
    __shared__ int idxl[128];
    const int t = threadIdx.x;
    const int b = blockIdx.x >> 9;
    const int n0 = (blockIdx.x & 511) << 3;
    const int tm = t & 15;           // edge group
    const int ct = (t >> 4) << 3;    // output channel base (0..120)
    const int elo = tm << 2;         // edges elo..elo+3
    const int ehi = 64 + (tm << 2);  // edges ehi..ehi+3

    if (t < 128) {
        bb[0][t] = bg1[t]; bb[1][t] = bg2[t]; bb[2][t] = bf2[t]; bb[3][t] = bf3[t];
        idxl[t] = idx2[((size_t)b * N_ + n0 + (t >> 4)) * 16 + (t & 15)];
    }
    if (t < 128) {
        int p = t >> 4, n = n0 + p, m = idxl[t];   // idxl[t] written by this thread
        const float* xc = xyz + ((size_t)b * N_ + n) * 3;
        const float* xk = xyz + ((size_t)b * N_ + m) * 3;
        float c0 = xc[0], c1v = xc[1], c2v = xc[2];
        float k0 = xk[0], k1 = xk[1], k2 = xk[2];
        float r0 = c0 - k0, r1 = c1v - k1, r2 = c2v - k2;
        G[0 * 128 + t] = sqrtf(r0 * r0 + r1 * r1 + r2 * r2);
        G[1 * 128 + t] = c0;  G[2 * 128 + t] = c1v; G[3 * 128 + t] = c2v;
        G[4 * 128 + t] = k0;  G[5 * 128 + t] = k1;  G[6 * 128 + t] = k2;
        G[7 * 128 + t] = r0;  G[8 * 128 + t] = r1;  G[9 * 128 + t] = r2;
    }
    __syncthreads();

    float acc[8][8];
    auto zacc = [&]() {
        #pragma unroll
        for (int ii = 0; ii < 8; ++ii)
            #pragma unroll
            for (int jj = 0; jj < 8; ++jj) acc[ii][jj] = 0.0f;
    };
    auto gemmG = [&](const float* __restrict__ WT) {   // K=128, A in LDS, W from L2; pipelined
        zacc();
        float w8[8], a8[8], w8n[8], a8n[8];
        *(float4*)&w8[0] = *(const float4*)(WT + ct);
        *(float4*)&w8[4] = *(const float4*)(WT + ct + 4);
        *(float4*)&a8[0] = *(const float4*)&A[elo];
        *(float4*)&a8[4] = *(const float4*)&A[ehi];
        #pragma unroll 4
        for (int i = 0; i < 128; ++i) {
            const int j = (i + 1) & 127;           // wraps once; harmless in-bounds read
            *(float4*)&w8n[0] = *(const float4*)(WT + (j << 7) + ct);
            *(float4*)&w8n[4] = *(const float4*)(WT + (j << 7) + ct + 4);
            *(float4*)&a8n[0] = *(const float4*)&A[(j << 7) + elo];
            *(float4*)&a8n[4] = *(const float4*)&A[(j << 7) + ehi];
            #pragma unroll
            for (int ii = 0; ii < 8; ++ii)
                #pragma unroll
                for (int jj = 0; jj < 8; ++jj)
                    acc[ii][jj] = fmaf(a8[ii], w8[jj], acc[ii][jj]);
            #pragma unroll
            for (int q = 0; q < 8; ++q) { w8[q] = w8n[q]; a8[q] = a8n[q]; }
        }
    };
    auto wbA = [&](const float* brow) {   // relu(acc + bias) -> A
        #pragma unroll
        for (int jj = 0; jj < 8; ++jj) {
            float bv = brow[ct + jj];
            float t0[4], t1[4];
            #pragma unroll
            for (int ii = 0; ii < 4; ++ii) {
                t0[ii] = fmaxf(acc[ii][jj] + bv, 0.0f);
                t1[ii] = fmaxf(acc[4 + ii][jj] + bv, 0.0f);
            }
            *(float4*)&A[(ct + jj) * 128 + elo] = *(float4*)t0;
            *(float4*)&A[(ct + jj) * 128 + ehi] = *(float4*)t1;
        }
    };

    // ---- g branch first ----
    zacc();
    #pragma unroll
    for (int i = 0; i < 10; ++i) {      // g1 (K=10)
        float a8[8], w8[8];
        *(float4*)&w8[0] = *(const float4*)(wg1t + (i << 7) + ct);
        *(float4*)&w8[4] = *(const float4*)(wg1t + (i << 7) + ct + 4);
        *(float4*)&a8[0] = *(const float4*)&G[(i << 7) + elo];
        *(float4*)&a8[4] = *(const float4*)&G[(i << 7) + ehi];
        #pragma unroll
        for (int ii = 0; ii < 8; ++ii)
            #pragma unroll
            for (int jj = 0; jj < 8; ++jj)
                acc[ii][jj] = fmaf(a8[ii], w8[jj], acc[ii][jj]);
    }
    wbA(bb[0]);
    __syncthreads();
    gemmG(wg2t);                        // g2 -> regs
    float g2r[8][8];
    #pragma unroll
    for (int ii = 0; ii < 8; ++ii)
        #pragma unroll
        for (int jj = 0; jj < 8; ++jj)
            g2r[ii][jj] = fmaxf(acc[ii][jj] + bb[1][ct + jj], 0.0f);
    __syncthreads();                    // all g2 reads of A done

    // ---- f branch: f1 = relu(Cf[n] + Pf[m]) gathered into A ----
    for (int it = 0; it < 16; ++it) {
        int idx = (it << 8) + t;
        int qq = idx >> 7, e = idx & 127;
        int n = n0 + (e >> 4);
        int m = idxl[e];
        const float4 cc = *(const float4*)(CfPf + ((size_t)b * N_ + n) * 256 + (qq << 2));
        const float4 pp = *(const float4*)(CfPf + ((size_t)b * N_ + m) * 256 + 128 + (qq << 2));
        A[((qq << 2) + 0) * 128 + e] = fmaxf(cc.x + pp.x, 0.0f);
        A[((qq << 2) + 1) * 128 + e] = fmaxf(cc.y + pp.y, 0.0f);
        A[((qq << 2) + 2) * 128 + e] = fmaxf(cc.z + pp.z, 0.0f);
        A[((qq << 2) + 3) * 128 + e] = fmaxf(cc.w + pp.w, 0.0f);
    }
    __syncthreads();

    gemmG(wf2t);                        // f2
    __syncthreads();                    // reads done before overwrite
    wbA(bb[2]);
    __syncthreads();
    gemmG(wf3t);                        // f3 -> combine with g2r

    float pl[8], ph[8];
    #pragma unroll
    for (int jj = 0; jj < 8; ++jj) {
        float bv = bb[3][ct + jj];
        float m0 = 0.0f, m1 = 0.0f;     // products are >= 0
        #pragma unroll
        for (int s = 0; s < 4; ++s) {
            m0 = fmaxf(m0, g2r[s][jj] * fmaxf(acc[s][jj] + bv, 0.0f));
            m1 = fmaxf(m1, g2r[4 + s][jj] * fmaxf(acc[4 + s][jj] + bv, 0.0f));
        }
        pl[jj] = m0; ph[jj] = m1;
    }
    // reduce over the 4 lanes sharing a point (t^1, t^2 stay in-wave)
    #pragma unroll
    for (int jj = 0; jj < 8; ++jj) {
        pl[jj] = fmaxf(pl[jj], __shfl_xor(pl[jj], 1));
        pl[jj] = fmaxf(pl[jj], __shfl_xor(pl[jj], 2));
        ph[jj] = fmaxf(ph[jj], __shfl_xor(ph[jj], 1));
        ph[jj] = fmaxf(ph[jj], __shfl_xor(ph[jj], 2));
    }
    if ((t & 3) == 0) {
        int p = tm >> 2;
        float* d0 = fea2 + ((size_t)b * N_ + n0 + p) * 128 + ct;
        *(float4*)d0 = *(float4*)&pl[0];
        *(float4*)(d0 + 4) = *(float4*)&pl[4];
        float* d1 = fea2 + ((size_t)b * N_ + n0 + 4 + p) * 128 + ct;
        *(float4*)d1 = *(float4*)&ph[0];
        *(float4*)(d1 + 4) = *(float4*)&ph[4];
    }
}

// ---------------------------------------------------------------- generic pointwise GEMM
// Y[m][o] = act(sum_i X[m][i]*WT[i][o] + bias); optional concat X1|X2; optional global-max epilogue
// LDS-staged weights; launch_bounds(256,3) for occupancy.

template<int RELU, int BMODE, int GMAX>
__global__ __launch_bounds__(256, 3) void gemm_pw(
    const float* __restrict__ X1, int S1, int K1,
    const float* __restrict__ X2, int S2, int Ktot,
    const float* __restrict__ WT, const float* __restrict__ bias,
    float* __restrict__ Y, int COUT, float* __restrict__ gout) {
    __shared__ __align__(16) float Xs[32][132];
    __shared__ __align__(16) float WsS[32][128];
    __shared__ float Pm[GMAX ? 2048 : 4];
    const int t = threadIdx.x;
    const int m0 = blockIdx.x * 128;
    const int o0 = blockIdx.y * 128;
    const int mt = (t & 15) * 8;
    const int ot = (t >> 4) * 8;
    float acc[8][8];
    #pragma unroll
    for (int ii = 0; ii < 8; ++ii)
        #pragma unroll
        for (int jj = 0; jj < 8; ++jj) acc[ii][jj] = 0.0f;

    const int ntile = Ktot / 32;
    for (int kt = 0; kt < ntile; ++kt) {
        int kbase = kt * 32;
        const float* Xp; int S, koff;
        if (kbase < K1) { Xp = X1; S = S1; koff = kbase; }
        else            { Xp = X2; S = S2; koff = kbase - K1; }
        #pragma unroll
        for (int rr = 0; rr < 4; ++rr) {
            int idx = t + rr * 256;
            int p = idx >> 3;
            int i4 = (idx & 7) * 4;
            const float4 v = *(const float4*)(Xp + (size_t)(m0 + p) * S + koff + i4);
            Xs[i4 + 0][p] = v.x; Xs[i4 + 1][p] = v.y; Xs[i4 + 2][p] = v.z; Xs[i4 + 3][p] = v.w;
        }
        #pragma unroll
        for (int rr = 0; rr < 4; ++rr) {
            int idx = t + rr * 256;
            int i = idx >> 5;
            int o4 = (idx & 31) * 4;
            *(float4*)&WsS[i][o4] = *(const float4*)(WT + (size_t)(kbase + i) * COUT + o0 + o4);
        }
        __syncthreads();
        #pragma unroll 4
        for (int i = 0; i < 32; ++i) {
            float a8[8], w8[8];
            *(float4*)&a8[0] = *(const float4*)&Xs[i][mt];
            *(float4*)&a8[4] = *(const float4*)&Xs[i][mt + 4];
            *(float4*)&w8[0] = *(const float4*)&WsS[i][ot];
            *(float4*)&w8[4] = *(const float4*)&WsS[i][ot + 4];
            #pragma unroll
            for (int ii = 0; ii < 8; ++ii)
                #pragma unroll
                for (int jj = 0; jj < 8; ++jj)
                    acc[ii][jj] = fmaf(a8[ii], w8[jj], acc[ii][jj]);
        }
        __syncthreads();
    }
    const int b = m0 / 4096;
    float bv[8];
    #pragma unroll
    for (int jj = 0; jj < 8; ++jj) {
        int o = o0 + ot + jj;
        bv[jj] = (BMODE == 0) ? bias[o] : bias[b * 512 + o];
    }
    if (GMAX) {
        #pragma unroll
        for (int jj = 0; jj < 8; ++jj) {
            float mx = 0.0f;
            #pragma unroll
            for (int ii = 0; ii < 8; ++ii) {
                float v = acc[ii][jj] + bv[jj];
                if (RELU) v = fmaxf(v, 0.0f);
                mx = fmaxf(mx, v);
            }
            Pm[(t & 15) * 128 + ot + jj] = mx;
        }
        __syncthreads();
        if (t < 128) {
            float mx = Pm[t];
            #pragma unroll
            for (int gg = 1; gg < 16; ++gg) mx = fmaxf(mx, Pm[gg * 128 + t]);
            atomicMax((unsigned int*)(gout + b * 1024 + o0 + t), __float_as_uint(mx));
        }
    } else {
        #pragma unroll
        for (int ii = 0; ii < 8; ++ii) {
            float outv[8];
            #pragma unroll
            for (int jj = 0; jj < 8; ++jj) {
                float v = acc[ii][jj] + bv[jj];
                if (RELU) v = fmaxf(v, 0.0f);
                outv[jj] = v;
            }
            float* yp = Y + (size_t)(m0 + mt + ii) * COUT + o0 + ot;
            *(float4*)yp = *(float4*)&outv[0];
            *(float4*)(yp + 4) = *(float4*)&outv[4];
        }
    }
}

// ---------------------------------------------------------------- bias3 = W_c3[:,160:] @ g + b_c3

__global__ void bias3_kernel(const float* __restrict__ g, const float* __restrict__ w_c3,
                             const float* __restrict__ b_c3, float* __restrict__ bias3) {
    __shared__ float gs[1024];
    int b = blockIdx.x >> 1;
    int o = ((blockIdx.x & 1) << 8) + threadIdx.x;
    for (int i = threadIdx.x; i < 1024; i += 256) gs[i] = g[b * 1024 + i];
    __syncthreads();
    float acc = b_c3[o];
    const float* wr = w_c3 + (size_t)o * 1184 + 160;
    for (int i = 0; i < 1024; i += 4) {
        float4 w4 = *(const float4*)(wr + i);
        acc = fmaf(w4.x, gs[i], acc);     acc = fmaf(w4.y, gs[i + 1], acc);
        acc = fmaf(w4.z, gs[i + 2], acc); acc = fmaf(w4.w, gs[i + 3], acc);
    }
    bias3[b * 512 + o] = acc;
}

// ---------------------------------------------------------------- final 128 -> 13 (no relu), output (B,13,N)

__global__ __launch_bounds__(256, 1) void c6_kernel(
    const float* __restrict__ h5, const float* __restrict__ w,
    const float* __restrict__ bias, float* __restrict__ out) {
    __shared__ float ws[13 * 128];
    __shared__ float bs[13];
    int t = threadIdx.x;
    for (int i = t; i < 13 * 128; i += 256) ws[i] = w[i];
    if (t < 13) bs[t] = bias[t];
    __syncthreads();
    int b = blockIdx.x >> 4;
    int n = ((blockIdx.x & 15) << 8) + t;
    float x[128];
    const float* xp = h5 + ((size_t)b * N_ + n) * 128;
    #pragma unroll
    for (int i = 0; i < 128; i += 4) *(float4*)&x[i] = *(const float4*)(xp + i);
    for (int o = 0; o < 13; ++o) {
        float acc = bs[o];
        #pragma unroll
        for (int i = 0; i < 128; ++i) acc = fmaf(ws[o * 128 + i], x[i], acc);
        out[((size_t)b * 13 + o) * N_ + n] = acc;
    }
}

// ---------------------------------------------------------------- launch

extern "C" void kernel_launch(void* const* d_in, const int* in_sizes, int n_in,
                              void* d_out, int out_size, void* d_ws, size_t ws_size,
                              hipStream_t stream) {
    (void)in_sizes; (void)n_in; (void)out_size; (void)ws_size;
    const float* xyz = (const float*)d_in[0];
    #define W_(j)  ((const float*)d_in[1 + 2 * (j)])
    #define Bp_(j) ((const float*)d_in[2 + 2 * (j)])

    char* ws = (char*)d_ws;
    const size_t MB = 1u << 20;
    int*   idx1  = (int*)(ws + 0 * MB);
    int*   idx2  = (int*)(ws + 2 * MB);
    float* fea1  = (float*)(ws + 4 * MB);
    float* CfPf  = (float*)(ws + 8 * MB);       // 32MB; reused later as h4
    float* fea2  = (float*)(ws + 40 * MB);
    float* h1    = (float*)(ws + 56 * MB);      // 16MB; reused later as h5
    float* sqbuf = (float*)(ws + 72 * MB);
    float* gbuf  = (float*)(ws + 72 * MB + (128u << 10));
    float* b3buf = (float*)(ws + 72 * MB + (160u << 10));
    float* wt    = (float*)(ws + 72 * MB + (176u << 10));
    float* h3    = (float*)(ws + 75 * MB);      // 64MB (also overlays knn Kbuf early)
    float* h4    = CfPf;
    float* h5    = h1;
    float* outp  = (float*)d_out;
    unsigned long long* Kbuf = (unsigned long long*)(ws + 75 * MB);  // 8.4MB, dead before h3

    float* wte1  = wt;            // 3584 (g1T, g2T @320, f1T @1344, f2T @1536, f3T @2560)
    float* wg1t2 = wt + 3584;     // 1280
    float* wtpre = wt + 4864;     // 8192
    float* bpre  = wt + 13056;    // 256
    float* wf2t  = wt + 13312;
    float* wf3t  = wt + 29696;
    float* wg2t  = wt + 46080;
    float* wc1t  = wt + 62464;
    float* wc2t  = wt + 78848;    // 131072
    float* wt3   = wt + 209920;   // 81920
    float* wt4   = wt + 291840;   // 131072
    float* wt5   = wt + 422912;   // 32768

    auto T = [&](const float* src, float* dst, int CO, int CI, int sstride) {
        int n = CO * CI;
        transpose_kernel<<<(n + 255) / 256, 256, 0, stream>>>(src, dst, CO, CI, sstride, 0);
    };
    T(W_(0),  wte1,        32,   10,  10);
    T(W_(1),  wte1 + 320,  32,   32,  32);
    T(W_(2),  wte1 + 1344, 32,   6,   6);
    T(W_(3),  wte1 + 1536, 32,   32,  32);
    T(W_(4),  wte1 + 2560, 32,   32,  32);
    T(W_(5),  wg1t2,       128,  10,  10);
    T(W_(8),  wf2t,        128,  128, 128);
    T(W_(9),  wf3t,        128,  128, 128);
    T(W_(6),  wg2t,        128,  128, 128);
    T(W_(10), wc1t,        128,  128, 128);
    T(W_(11), wc2t,        1024, 128, 128);
    transpose_kernel<<<(512 * 160 + 255) / 256, 256, 0, stream>>>(W_(12), wt3, 512, 160, 1184, 0);
    T(W_(13), wt4,         256,  512, 512);
    T(W_(14), wt5,         128,  256, 256);
    prep_pre_kernel<<<33, 256, 0, stream>>>(W_(7), Bp_(7), wtpre, bpre);
    zero_kernel<<<32, 256, 0, stream>>>(gbuf, 8192);

    // knn1 + edgeconv1
    sq_kernel<3><<<128, 256, 0, stream>>>(xyz, sqbuf);
    knn_kernel<3><<<dim3(64, 8, 2), 256, 0, stream>>>(xyz, sqbuf, Kbuf);
    knn_merge_kernel<<<128, 256, 0, stream>>>(Kbuf, idx1);
    e1_kernel<<<4096, 256, 0, stream>>>(xyz, idx1, wte1, Bp_(0), Bp_(1), Bp_(2), Bp_(3), Bp_(4), fea1);

    // knn2 + edgeconv2
    sq_kernel<32><<<128, 256, 0, stream>>>(fea1, sqbuf);
    knn_kernel<32><<<dim3(64, 8, 2), 256, 0, stream>>>(fea1, sqbuf, Kbuf);
    knn_merge_kernel<<<128, 256, 0, stream>>>(Kbuf, idx2);
    gemm_pw<0, 0, 0><<<dim3(256, 2), 256, 0, stream>>>(fea1, 32, 32, nullptr, 0, 32,
                                                       wtpre, bpre, CfPf, 256, nullptr);
    e2_kernel<<<4096, 256, 0, stream>>>(xyz, idx2, CfPf, wg1t2, wg2t, wf2t, wf3t,
                                        Bp_(5), Bp_(6), Bp_(8), Bp_(9), fea2);

    // head
    gemm_pw<1, 0, 0><<<dim3(256, 1), 256, 0, stream>>>(fea2, 128, 128, nullptr, 0, 128,
                                                       wc1t, Bp_(10), h1, 128, nullptr);
    gemm_pw<1, 0, 1><<<dim3(256, 8), 256, 0, stream>>>(h1, 128, 128, nullptr, 0, 128,
                                                       wc2t, Bp_(11), nullptr, 1024, gbuf);
    bias3_kernel<<<16, 256, 0, stream>>>(gbuf, W_(12), Bp_(12), b3buf);
    gemm_pw<1, 1, 0><<<dim3(256, 4), 256, 0, stream>>>(fea1, 32, 32, fea2, 128, 160,
                                                       wt3, b3buf, h3, 512, nullptr);
    gemm_pw<1, 0, 0><<<dim3(256, 2), 256, 0, stream>>>(h3, 512, 512, nullptr, 0, 512,
                                                       wt4, Bp_(13), h4, 256, nullptr);
    gemm_pw<1, 0, 0><<<dim3(256, 1), 256, 0, stream>>>(h4, 256, 256, nullptr, 0, 256,
                                                       wt5, Bp_(14), h5, 128, nullptr);
    c6_kernel<<<128, 256, 0, stream>>>(h5, W_(15), Bp_(15), outp);
    #undef W_
    #undef Bp_
}

// Round 11
// 1676.826 us; speedup vs baseline: 1.0646x; 1.0646x over previous
//
#include <hip/hip_runtime.h>
#include <math.h>

#define B_ 8
#define N_ 4096

// ---------------------------------------------------------------- unified prep kernel
// All weight transposes + wtpre/bpre build + gbuf zero + sq(xyz) in ONE dispatch
// (replaces 17 tiny serialized launches). dst[i*CO+o] = src[o*sstride+i] per segment.

__global__ __launch_bounds__(256) void prep_kernel(
    const float* __restrict__ w0, const float* __restrict__ w1,
    const float* __restrict__ w2, const float* __restrict__ w3,
    const float* __restrict__ w4, const float* __restrict__ w5,
    const float* __restrict__ w6, const float* __restrict__ w8,
    const float* __restrict__ w9, const float* __restrict__ w10,
    const float* __restrict__ w11, const float* __restrict__ w12,
    const float* __restrict__ w13, const float* __restrict__ w14,
    const float* __restrict__ wf1, const float* __restrict__ bf1,
    const float* __restrict__ xyz,
    float* __restrict__ wt, float* __restrict__ gbuf, float* __restrict__ sqbuf) {
    const int g = blockIdx.x * 256 + threadIdx.x;
    float* wte1  = wt;
    float* wg1t2 = wt + 3584;
    float* wtpre = wt + 4864;
    float* bpre  = wt + 13056;
    float* wf2t  = wt + 13312;
    float* wf3t  = wt + 29696;
    float* wg2t  = wt + 46080;
    float* wc1t  = wt + 62464;
    float* wc2t  = wt + 78848;
    float* wt3   = wt + 209920;
    float* wt4   = wt + 291840;
    float* wt5   = wt + 422912;

    if (g < 320)            { int i = g >> 5, o = g & 31;                 wte1[g] = w0[o * 10 + i]; }
    else if (g < 1344)      { int l = g - 320;    int i = l >> 5,  o = l & 31;   wte1[320 + l]  = w1[o * 32 + i]; }
    else if (g < 1536)      { int l = g - 1344;   int i = l >> 5,  o = l & 31;   wte1[1344 + l] = w2[o * 6 + i]; }
    else if (g < 2560)      { int l = g - 1536;   int i = l >> 5,  o = l & 31;   wte1[1536 + l] = w3[o * 32 + i]; }
    else if (g < 3584)      { int l = g - 2560;   int i = l >> 5,  o = l & 31;   wte1[2560 + l] = w4[o * 32 + i]; }
    else if (g < 4864)      { int l = g - 3584;   int i = l >> 7,  o = l & 127;  wg1t2[l] = w5[o * 10 + i]; }
    else if (g < 21248)     { int l = g - 4864;   int i = l >> 7,  o = l & 127;  wf2t[l]  = w8[o * 128 + i]; }
    else if (g < 37632)     { int l = g - 21248;  int i = l >> 7,  o = l & 127;  wf3t[l]  = w9[o * 128 + i]; }
    else if (g < 54016)     { int l = g - 37632;  int i = l >> 7,  o = l & 127;  wg2t[l]  = w6[o * 128 + i]; }
    else if (g < 70400)     { int l = g - 54016;  int i = l >> 7,  o = l & 127;  wc1t[l]  = w10[o * 128 + i]; }
    else if (g < 201472)    { int l = g - 70400;  int i = l >> 10, o = l & 1023; wc2t[l]  = w11[o * 128 + i]; }
    else if (g < 283392)    { int l = g - 201472; int i = l >> 9,  o = l & 511;  wt3[l]   = w12[o * 1184 + i]; }
    else if (g < 414464)    { int l = g - 283392; int i = l >> 8,  o = l & 255;  wt4[l]   = w13[o * 512 + i]; }
    else if (g < 447232)    { int l = g - 414464; int i = l >> 7,  o = l & 127;  wt5[l]   = w14[o * 256 + i]; }
    else if (g < 455424)    { int l = g - 447232; int c = l >> 8,  o = l & 255;
                              wtpre[l] = (o < 128) ? wf1[o * 64 + c] : wf1[(o - 128) * 64 + 32 + c]; }
    else if (g < 455680)    { int l = g - 455424; bpre[l] = (l < 128) ? bf1[l] : 0.0f; }
    else if (g < 463872)    { gbuf[g - 455680] = 0.0f; }
    else if (g < 496640)    { int l = g - 463872;
                              const float* p = xyz + (size_t)l * 3;
                              sqbuf[l] = fmaf(p[0], p[0], fmaf(p[1], p[1], p[2] * p[2])); }
}

template<int C>
__global__ void sq_kernel(const float* __restrict__ F, float* __restrict__ SQ) {
    int idx = blockIdx.x * 256 + threadIdx.x;
    const float* p = F + (size_t)idx * C;
    float s = 0.0f;
    #pragma unroll
    for (int c = 0; c < C; ++c) s = fmaf(p[c], p[c], s);
    SQ[idx] = s;
}

// ---------------------------------------------------------------- knn (top-16 nearest)
// Hot loop: branchless bitonic top-k on FLOAT keys + int index payload. Block-end /
// inter-half merges use the exact u64 (ord<<32 | 4095-col) format.

__device__ __forceinline__ void cas_asc(unsigned long long& x, unsigned long long& y) {
    unsigned long long a = x, b = y;
    bool sw = a > b;
    x = sw ? b : a;
    y = sw ? a : b;
}

// k, o both asc-sorted; k <- top-16 of (k U o), asc-sorted
__device__ __forceinline__ void merge_top(unsigned long long (&k)[16],
                                          const unsigned long long (&o)[16]) {
    #pragma unroll
    for (int i = 0; i < 16; ++i) {
        unsigned long long bb = o[15 - i];
        if (bb > k[i]) k[i] = bb;         // k now bitonic, holds top-16 multiset
    }
    #pragma unroll
    for (int st = 8; st >= 1; st >>= 1)   // bitonic clean -> asc
        #pragma unroll
        for (int i = 0; i < 16; ++i)
            if ((i & st) == 0) cas_asc(k[i], k[i + st]);
}

__device__ __forceinline__ void casf(float& x, float& y, int& xi, int& yi) {
    bool sw = x > y;
    float a = sw ? y : x;  float b = sw ? x : y;
    int ai = sw ? yi : xi; int bi = sw ? xi : yi;
    x = a; y = b; xi = ai; yi = bi;
}

// full bitonic sort, ascending by value
__device__ __forceinline__ void sort16f(float (&v)[16], int (&ix)[16]) {
    #pragma unroll
    for (int sz = 2; sz <= 16; sz <<= 1)
        #pragma unroll
        for (int st = sz >> 1; st >= 1; st >>= 1)
            #pragma unroll
            for (int i = 0; i < 16; ++i)
                if ((i & st) == 0) {
                    if ((i & sz) == 0) casf(v[i], v[i + st], ix[i], ix[i + st]);
                    else                casf(v[i + st], v[i], ix[i + st], ix[i]);
                }
}

// kv/ki asc-sorted running top-16; nv/ni asc-sorted candidates
__device__ __forceinline__ void merge_topf(float (&kv)[16], int (&ki)[16],
                                           const float (&nv)[16], const int (&ni)[16]) {
    #pragma unroll
    for (int i = 0; i < 16; ++i) {
        bool tk = nv[15 - i] > kv[i];
        kv[i] = tk ? nv[15 - i] : kv[i];
        ki[i] = tk ? ni[15 - i] : ki[i];
    }
    #pragma unroll
    for (int st = 8; st >= 1; st >>= 1)
        #pragma unroll
        for (int i = 0; i < 16; ++i)
            if ((i & st) == 0) casf(kv[i], kv[i + st], ki[i], ki[i + st]);
}

template<int C>
__global__ __launch_bounds__(256, 3) void knn_kernel(
    const float* __restrict__ F, const float* __restrict__ SQ,
    unsigned long long* __restrict__ Kout) {
    // phase1 overlay: Rf[C*68] | Cf[C*68] | Ds[64*72]; phase2 overlay: QL[64*65] (u64)
    constexpr int P1F = 2 * C * 68 + 64 * 72;                       // floats
    constexpr int P1W = (P1F + 1) / 2;                              // u64 words
    constexpr int SMW = (P1W > 64 * 65) ? P1W : 64 * 65;
    __shared__ __align__(16) unsigned long long SM[SMW];
    __shared__ float sqr[64];
    __shared__ float sqc[64];
    float* Rf = (float*)SM;
    float* Cf = Rf + C * 68;
    float* Ds = Cf + C * 68;                                        // stride 72
    const int t = threadIdx.x;
    const int b = blockIdx.y;
    const int r0 = blockIdx.x * 64;
    const int half = blockIdx.z;
    const int H0 = half * 2048;
    const int rt = (t & 15) * 4, ct = (t >> 4) * 4;                 // gemm tile
    const int sr = t & 63, sq = t >> 6;                             // selection row/quarter

    for (int idx = t; idx < 64 * C; idx += 256) {
        int rr = idx / C, c = idx - rr * C;
        Rf[c * 68 + rr] = F[((size_t)b * N_ + r0 + rr) * C + c];
    }
    if (t < 64) sqr[t] = SQ[(size_t)b * N_ + r0 + t];

    float kv[16]; int ki[16];
    #pragma unroll
    for (int j = 0; j < 16; ++j) { kv[j] = -3.4e38f; ki[j] = 0; }

    for (int c0 = H0; c0 < H0 + 2048; c0 += 64) {
        for (int idx = t; idx < 64 * C; idx += 256) {
            int cc = idx / C, c = idx - cc * C;
            Cf[c * 68 + cc] = F[((size_t)b * N_ + c0 + cc) * C + c];
        }
        if (t < 64) sqc[t] = SQ[(size_t)b * N_ + c0 + t];
        __syncthreads();                          // staging ready; prev rescans done

        float acc[4][4];
        #pragma unroll
        for (int ii = 0; ii < 4; ++ii)
            #pragma unroll
            for (int jj = 0; jj < 4; ++jj) acc[ii][jj] = 0.0f;
        #pragma unroll
        for (int i = 0; i < C; ++i) {
            float a4[4], w4[4];
            *(float4*)a4 = *(const float4*)&Rf[i * 68 + rt];
            *(float4*)w4 = *(const float4*)&Cf[i * 68 + ct];
            #pragma unroll
            for (int ii = 0; ii < 4; ++ii)
                #pragma unroll
                for (int jj = 0; jj < 4; ++jj)
                    acc[ii][jj] = fmaf(a4[ii], w4[jj], acc[ii][jj]);
        }
        #pragma unroll
        for (int ii = 0; ii < 4; ++ii) {
            float e[4];
            #pragma unroll
            for (int jj = 0; jj < 4; ++jj)
                e[jj] = 2.0f * acc[ii][jj] - sqr[rt + ii] - sqc[ct + jj];
            *(float2*)&Ds[(rt + ii) * 72 + ct] = make_float2(e[0], e[1]);
            *(float2*)&Ds[(rt + ii) * 72 + ct + 2] = make_float2(e[2], e[3]);
        }
        __syncthreads();                          // Ds ready

        // rescan own 16 values, float-key bitonic update
        float nv[16]; int ni[16];
        *(float4*)&nv[0]  = *(const float4*)&Ds[sr * 72 + sq * 16 + 0];
        *(float4*)&nv[4]  = *(const float4*)&Ds[sr * 72 + sq * 16 + 4];
        *(float4*)&nv[8]  = *(const float4*)&Ds[sr * 72 + sq * 16 + 8];
        *(float4*)&nv[12] = *(const float4*)&Ds[sr * 72 + sq * 16 + 12];
        #pragma unroll
        for (int s = 0; s < 16; ++s) ni[s] = c0 + sq * 16 + s;
        sort16f(nv, ni);
        merge_topf(kv, ki, nv, ni);
    }
    __syncthreads();                              // all rescans done before overlay reuse
    // pack to exact-order u64 keys for the merge phases
    unsigned long long kl[16];
    #pragma unroll
    for (int j = 0; j < 16; ++j) {
        unsigned int u = __float_as_uint(kv[j]);
        unsigned int ou = (u & 0x80000000u) ? ~u : (u | 0x80000000u);
        kl[j] = ((unsigned long long)ou << 32) | (unsigned int)(4095 - ki[j]);
    }
    unsigned long long* QL = SM;
    #pragma unroll
    for (int j = 0; j < 16; ++j) QL[sr * 65 + sq * 16 + j] = kl[j];
    __syncthreads();
    if (t < 64) {
        unsigned long long K[16], Tt[16];
        #pragma unroll
        for (int j = 0; j < 16; ++j) K[j] = QL[t * 65 + j];
        #pragma unroll
        for (int q = 1; q < 4; ++q) {
            #pragma unroll
            for (int j = 0; j < 16; ++j) Tt[j] = QL[t * 65 + q * 16 + j];
            merge_top(K, Tt);
        }
        size_t obase = (((size_t)b * 2 + half) * N_ + r0 + t) * 16;
        #pragma unroll
        for (int j = 0; j < 16; ++j) Kout[obase + j] = K[j];
    }
}

__global__ __launch_bounds__(256) void knn_merge_kernel(
    const unsigned long long* __restrict__ Kbuf, int* __restrict__ IDX) {
    int gid = blockIdx.x * 256 + threadIdx.x;     // 0..32767
    int b = gid >> 12, r = gid & 4095;
    unsigned long long K0[16], K1[16];
    const unsigned long long* p0 = Kbuf + (((size_t)b * 2 + 0) * N_ + r) * 16;
    const unsigned long long* p1 = Kbuf + (((size_t)b * 2 + 1) * N_ + r) * 16;
    #pragma unroll
    for (int j = 0; j < 16; ++j) { K0[j] = p0[j]; K1[j] = p1[j]; }
    merge_top(K0, K1);
    size_t ob = ((size_t)b * N_ + r) * 16;
    #pragma unroll
    for (int j = 0; j < 16; ++j)
        IDX[ob + j] = 4095 - (int)(unsigned int)(K0[15 - j] & 0xFFFFFFFFu);
}

// ---------------------------------------------------------------- edgeconv 1 (xyz, C=3 -> 32)

__global__ __launch_bounds__(256, 4) void e1_kernel(
    const float* __restrict__ xyz, const int* __restrict__ idx1,
    const float* __restrict__ wte1,
    const float* __restrict__ bg1, const float* __restrict__ bg2,
    const float* __restrict__ bf1, const float* __restrict__ bf2,
    const float* __restrict__ bf3,
    float* __restrict__ fea1) {
    __shared__ __align__(16) float Ain[10 * 132];
    __shared__ __align__(16) float Bu0[32 * 132];
    __shared__ __align__(16) float Bu1[32 * 132];
    __shared__ __align__(16) float wl[3584];
    __shared__ float bl[5][32];
    __shared__ __align__(16) float Pm1[4][8][32];
    __shared__ int idxl[128];
    const int t = threadIdx.x;
    const int b = blockIdx.x >> 9;
    const int n0 = (blockIdx.x & 511) << 3;
    const int et = (t & 31) << 2;
    const int ct = (t >> 5) << 2;

    for (int i = t; i < 3584; i += 256) wl[i] = wte1[i];
    if (t < 32) {
        bl[0][t] = bg1[t]; bl[1][t] = bg2[t]; bl[2][t] = bf1[t];
        bl[3][t] = bf2[t]; bl[4][t] = bf3[t];
    }
    if (t < 128) idxl[t] = idx1[((size_t)b * N_ + n0 + (t >> 4)) * 16 + (t & 15)];
    __syncthreads();
    if (t < 128) {
        int p = t >> 4, n = n0 + p, m = idxl[t];
        const float* xc = xyz + ((size_t)b * N_ + n) * 3;
        const float* xk = xyz + ((size_t)b * N_ + m) * 3;
        float c0 = xc[0], c1v = xc[1], c2v = xc[2];
        float k0 = xk[0], k1 = xk[1], k2 = xk[2];
        float r0 = c0 - k0, r1 = c1v - k1, r2 = c2v - k2;
        Ain[0 * 132 + t] = sqrtf(r0 * r0 + r1 * r1 + r2 * r2);
        Ain[1 * 132 + t] = c0;  Ain[2 * 132 + t] = c1v; Ain[3 * 132 + t] = c2v;
        Ain[4 * 132 + t] = k0;  Ain[5 * 132 + t] = k1;  Ain[6 * 132 + t] = k2;
        Ain[7 * 132 + t] = r0;  Ain[8 * 132 + t] = r1;  Ain[9 * 132 + t] = r2;
    }
    __syncthreads();

    float acc[4][4];
    auto gem = [&](int KK, const float* Asrc, int woff) {
        #pragma unroll
        for (int ii = 0; ii < 4; ++ii)
            #pragma unroll
            for (int jj = 0; jj < 4; ++jj) acc[ii][jj] = 0.0f;
        for (int i = 0; i < KK; ++i) {
            float a4[4], w4[4];
            *(float4*)a4 = *(const float4*)&Asrc[i * 132 + et];
            *(float4*)w4 = *(const float4*)&wl[woff + i * 32 + ct];
            #pragma unroll
            for (int ii = 0; ii < 4; ++ii)
                #pragma unroll
                for (int jj = 0; jj < 4; ++jj)
                    acc[ii][jj] = fmaf(a4[ii], w4[jj], acc[ii][jj]);
        }
    };
    auto wrout = [&](float* dst, const float* brow) {
        #pragma unroll
        for (int jj = 0; jj < 4; ++jj) {
            float tmp[4];
            #pragma unroll
            for (int ii = 0; ii < 4; ++ii) tmp[ii] = fmaxf(acc[ii][jj] + brow[ct + jj], 0.0f);
            *(float4*)&dst[(ct + jj) * 132 + et] = *(float4*)tmp;
        }
    };

    gem(10, Ain, 0);          wrout(Bu1, bl[0]);   __syncthreads();   // g1
    gem(32, Bu1, 320);                                                // g2 -> regs
    float g2r[4][4];
    #pragma unroll
    for (int ii = 0; ii < 4; ++ii)
        #pragma unroll
        for (int jj = 0; jj < 4; ++jj)
            g2r[ii][jj] = fmaxf(acc[ii][jj] + bl[1][ct + jj], 0.0f);
    gem(6, Ain + 132, 1344);  wrout(Bu0, bl[2]);   __syncthreads();   // f1
    gem(32, Bu0, 1536);       wrout(Bu1, bl[3]);   __syncthreads();   // f2
    gem(32, Bu1, 2560);                                               // f3

    float pm[4];
    #pragma unroll
    for (int jj = 0; jj < 4; ++jj) {
        float mx = 0.0f;
        #pragma unroll
        for (int ii = 0; ii < 4; ++ii) {
            float f3 = fmaxf(acc[ii][jj] + bl[4][ct + jj], 0.0f);
            mx = fmaxf(mx, g2r[ii][jj] * f3);
        }
        pm[jj] = mx;
    }
    const int sub = t & 3, pl = (t & 31) >> 2;
    *(float4*)&Pm1[sub][pl][ct] = *(float4*)pm;
    __syncthreads();
    {
        int p = t >> 5, c = t & 31;
        float v = fmaxf(fmaxf(Pm1[0][p][c], Pm1[1][p][c]), fmaxf(Pm1[2][p][c], Pm1[3][p][c]));
        fea1[((size_t)b * N_ + n0 + p) * 32 + c] = v;
    }
}

// ---------------------------------------------------------------- edgeconv 2 main (per-edge 128-wide MLPs)
// R7 configuration (measured best): 8 points / 128 edges per block, 2 blocks/CU,
// K-loop software-pipelined (next-k weight + A fragments prefetched into registers).

__global__ __launch_bounds__(256, 2) void e2_kernel(
    const float* __restrict__ xyz, const int* __restrict__ idx2,
    const float* __restrict__ CfPf,
    const float* __restrict__ wg1t, const float* __restrict__ wg2t,
    const float* __restrict__ wf2t, const float* __restrict__ wf3t,
    const float* __restrict__ bg1, const float* __restrict__ bg2,
    const float* __restrict__ bf2, const float* __restrict__ bf3,
    float* __restrict__ fea2) {
    __shared__ __align__(16) float A[128 * 128];   // 64KB, stride 128, channel-major
    __shared__ __align__(16) float G[10 * 128];    // 5KB geometry
    __shared__ float bb[4][128];
    __shared__ int idxl[128];
    const int t = threadIdx.x;
    const int b = blockIdx.x >> 9;
    const int n0 = (blockIdx.x & 511) << 3;
    const int tm = t & 15;           // edge group
    const int ct = (t >> 4) << 3;    // output channel base (0..120)
    const int elo = tm << 2;         // edges elo..elo+3
    const int ehi = 64 + (tm << 2);  // edges ehi..ehi+3

    if (t < 128) {
        bb[0][t] = bg1[t]; bb[1][t] = bg2[t]; bb[2][t] = bf2[t]; bb[3][t] = bf3[t];
        idxl[t] = idx2[((size_t)b * N_ + n0 + (t >> 4)) * 16 + (t & 15)];
    }
    if (t < 128) {
        int p = t >> 4, n = n0 + p, m = idxl[t];   // idxl[t] written by this thread
        const float* xc = xyz + ((size_t)b * N_ + n) * 3;
        const float* xk = xyz + ((size_t)b * N_ + m) * 3;
        float c0 = xc[0], c1v = xc[1], c2v = xc[2];
        float k0 = xk[0], k1 = xk[1], k2 = xk[2];
        float r0 = c0 - k0, r1 = c1v - k1, r2 = c2v - k2;
        G[0 * 128 + t] = sqrtf(r0 * r0 + r1 * r1 + r2 * r2);
        G[1 * 128 + t] = c0;  G[2 * 128 + t] = c1v; G[3 * 128 + t] = c2v;
        G[4 * 128 + t] = k0;  G[5 * 128 + t] = k1;  G[6 * 128 + t] = k2;
        G[7 * 128 + t] = r0;  G[8 * 128 + t] = r1;  G[9 * 128 + t] = r2;
    }
    __syncthreads();

    float acc[8][8];
    auto zacc = [&]() {
        #pragma unroll
        for (int ii = 0; ii < 8; ++ii)
            #pragma unroll
            for (int jj = 0; jj < 8; ++jj) acc[ii][jj] = 0.0f;
    };
    auto gemmG = [&](const float* __restrict__ WT) {   // K=128, A in LDS, W from L2; pipelined
        zacc();
        float w8[8], a8[8], w8n[8], a8n[8];
        *(float4*)&w8[0] = *(const float4*)(WT + ct);
        *(float4*)&w8[4] = *(const float4*)(WT + ct + 4);
        *(float4*)&a8[0] = *(const float4*)&A[elo];
        *(float4*)&a8[4] = *(const float4*)&A[ehi];
        #pragma unroll 4
        for (int i = 0; i < 128; ++i) {
            const int j = (i + 1) & 127;           // wraps once; harmless in-bounds read
            *(float4*)&w8n[0] = *(const float4*)(WT + (j << 7) + ct);
            *(float4*)&w8n[4] = *(const float4*)(WT + (j << 7) + ct + 4);
            *(float4*)&a8n[0] = *(const float4*)&A[(j << 7) + elo];
            *(float4*)&a8n[4] = *(const float4*)&A[(j << 7) + ehi];
            #pragma unroll
            for (int ii = 0; ii < 8; ++ii)
                #pragma unroll
                for (int jj = 0; jj < 8; ++jj)
                    acc[ii][jj] = fmaf(a8[ii], w8[jj], acc[ii][jj]);
            #pragma unroll
            for (int q = 0; q < 8; ++q) { w8[q] = w8n[q]; a8[q] = a8n[q]; }
        }
    };
    auto wbA = [&](const float* brow) {   // relu(acc + bias) -> A
        #pragma unroll
        for (int jj = 0; jj < 8; ++jj) {
            float bv = brow[ct + jj];
            float t0[4], t1[4];
            #pragma unroll
            for (int ii = 0; ii < 4; ++ii) {
                t0[ii] = fmaxf(acc[ii][jj] + bv, 0.0f);
                t1[ii] = fmaxf(acc[4 + ii][jj] + bv, 0.0f);
            }
            *(float4*)&A[(ct + jj) * 128 + elo] = *(float4*)t0;
            *(float4*)&A[(ct + jj) * 128 + ehi] = *(float4*)t1;
        }
    };

    // ---- g branch first ----
    zacc();
    #pragma unroll
    for (int i = 0; i < 10; ++i) {      // g1 (K=10)
        float a8[8], w8[8];
        *(float4*)&w8[0] = *(const float4*)(wg1t + (i << 7) + ct);
        *(float4*)&w8[4] = *(const float4*)(wg1t + (i << 7) + ct + 4);
        *(float4*)&a8[0] = *(const float4*)&G[(i << 7) + elo];
        *(float4*)&a8[4] = *(const float4*)&G[(i << 7) + ehi];
        #pragma unroll
        for (int ii = 0; ii < 8; ++ii)
            #pragma unroll
            for (int jj = 0; jj < 8; ++jj)
                acc[ii][jj] = fmaf(a8[ii], w8[jj], acc[ii][jj]);
    }
    wbA(bb[0]);
    __syncthreads();
    gemmG(wg2t);                        // g2 -> regs
    float g2r[8][8];
    #pragma unroll
    for (int ii = 0; ii < 8; ++ii)
        #pragma unroll
        for (int jj = 0; jj < 8; ++jj)
            g2r[ii][jj] = fmaxf(acc[ii][jj] + bb[1][ct + jj], 0.0f);
    __syncthreads();                    // all g2 reads of A done

    // ---- f branch: f1 = relu(Cf[n] + Pf[m]) gathered into A ----
    for (int it = 0; it < 16; ++it) {
        int idx = (it << 8) + t;
        int qq = idx >> 7, e = idx & 127;
        int n = n0 + (e >> 4);
        int m = idxl[e];
        const float4 cc = *(const float4*)(CfPf + ((size_t)b * N_ + n) * 256 + (qq << 2));
        const float4 pp = *(const float4*)(CfPf + ((size_t)b * N_ + m) * 256 + 128 + (qq << 2));
        A[((qq << 2) + 0) * 128 + e] = fmaxf(cc.x + pp.x, 0.0f);
        A[((qq << 2) + 1) * 128 + e] = fmaxf(cc.y + pp.y, 0.0f);
        A[((qq << 2) + 2) * 128 + e] = fmaxf(cc.z + pp.z, 0.0f);
        A[((qq << 2) + 3) * 128 + e] = fmaxf(cc.w + pp.w, 0.0f);
    }
    __syncthreads();

    gemmG(wf2t);                        // f2
    __syncthreads();                    // reads done before overwrite
    wbA(bb[2]);
    __syncthreads();
    gemmG(wf3t);                        // f3 -> combine with g2r

    float pl[8], ph[8];
    #pragma unroll
    for (int jj = 0; jj < 8; ++jj) {
        float bv = bb[3][ct + jj];
        float m0 = 0.0f, m1 = 0.0f;     // products are >= 0
        #pragma unroll
        for (int s = 0; s < 4; ++s) {
            m0 = fmaxf(m0, g2r[s][jj] * fmaxf(acc[s][jj] + bv, 0.0f));
            m1 = fmaxf(m1, g2r[4 + s][jj] * fmaxf(acc[4 + s][jj] + bv, 0.0f));
        }
        pl[jj] = m0; ph[jj] = m1;
    }
    // reduce over the 4 lanes sharing a point (t^1, t^2 stay in-wave)
    #pragma unroll
    for (int jj = 0; jj < 8; ++jj) {
        pl[jj] = fmaxf(pl[jj], __shfl_xor(pl[jj], 1));
        pl[jj] = fmaxf(pl[jj], __shfl_xor(pl[jj], 2));
        ph[jj] = fmaxf(ph[jj], __shfl_xor(ph[jj], 1));
        ph[jj] = fmaxf(ph[jj], __shfl_xor(ph[jj], 2));
    }
    if ((t & 3) == 0) {
        int p = tm >> 2;
        float* d0 = fea2 + ((size_t)b * N_ + n0 + p) * 128 + ct;
        *(float4*)d0 = *(float4*)&pl[0];
        *(float4*)(d0 + 4) = *(float4*)&pl[4];
        float* d1 = fea2 + ((size_t)b * N_ + n0 + 4 + p) * 128 + ct;
        *(float4*)d1 = *(float4*)&ph[0];
        *(float4*)(d1 + 4) = *(float4*)&ph[4];
    }
}

// ---------------------------------------------------------------- generic pointwise GEMM
// Y[m][o] = act(sum_i X[m][i]*WT[i][o] + bias); optional concat X1|X2; optional global-max epilogue
// LDS-staged weights; launch_bounds(256,3) for occupancy.

template<int RELU, int BMODE, int GMAX>
__global__ __launch_bounds__(256, 3) void gemm_pw(
    const float* __restrict__ X1, int S1, int K1,
    const float* __restrict__ X2, int S2, int Ktot,
    const float* __restrict__ WT, const float* __restrict__ bias,
    float* __restrict__ Y, int COUT, float* __restrict__ gout) {
    __shared__ __align__(16) float Xs[32][132];
    __shared__ __align__(16) float WsS[32][128];
    __shared__ float Pm[GMAX ? 2048 : 4];
    const int t = threadIdx.x;
    const int m0 = blockIdx.x * 128;
    const int o0 = blockIdx.y * 128;
    const int mt = (t & 15) * 8;
    const int ot = (t >> 4) * 8;
    float acc[8][8];
    #pragma unroll
    for (int ii = 0; ii < 8; ++ii)
        #pragma unroll
        for (int jj = 0; jj < 8; ++jj) acc[ii][jj] = 0.0f;

    const int ntile = Ktot / 32;
    for (int kt = 0; kt < ntile; ++kt) {
        int kbase = kt * 32;
        const float* Xp; int S, koff;
        if (kbase < K1) { Xp = X1; S = S1; koff = kbase; }
        else            { Xp = X2; S = S2; koff = kbase - K1; }
        #pragma unroll
        for (int rr = 0; rr < 4; ++rr) {
            int idx = t + rr * 256;
            int p = idx >> 3;
            int i4 = (idx & 7) * 4;
            const float4 v = *(const float4*)(Xp + (size_t)(m0 + p) * S + koff + i4);
            Xs[i4 + 0][p] = v.x; Xs[i4 + 1][p] = v.y; Xs[i4 + 2][p] = v.z; Xs[i4 + 3][p] = v.w;
        }
        #pragma unroll
        for (int rr = 0; rr < 4; ++rr) {
            int idx = t + rr * 256;
            int i = idx >> 5;
            int o4 = (idx & 31) * 4;
            *(float4*)&WsS[i][o4] = *(const float4*)(WT + (size_t)(kbase + i) * COUT + o0 + o4);
        }
        __syncthreads();
        #pragma unroll 4
        for (int i = 0; i < 32; ++i) {
            float a8[8], w8[8];
            *(float4*)&a8[0] = *(const float4*)&Xs[i][mt];
            *(float4*)&a8[4] = *(const float4*)&Xs[i][mt + 4];
            *(float4*)&w8[0] = *(const float4*)&WsS[i][ot];
            *(float4*)&w8[4] = *(const float4*)&WsS[i][ot + 4];
            #pragma unroll
            for (int ii = 0; ii < 8; ++ii)
                #pragma unroll
                for (int jj = 0; jj < 8; ++jj)
                    acc[ii][jj] = fmaf(a8[ii], w8[jj], acc[ii][jj]);
        }
        __syncthreads();
    }
    const int b = m0 / 4096;
    float bv[8];
    #pragma unroll
    for (int jj = 0; jj < 8; ++jj) {
        int o = o0 + ot + jj;
        bv[jj] = (BMODE == 0) ? bias[o] : bias[b * 512 + o];
    }
    if (GMAX) {
        #pragma unroll
        for (int jj = 0; jj < 8; ++jj) {
            float mx = 0.0f;
            #pragma unroll
            for (int ii = 0; ii < 8; ++ii) {
                float v = acc[ii][jj] + bv[jj];
                if (RELU) v = fmaxf(v, 0.0f);
                mx = fmaxf(mx, v);
            }
            Pm[(t & 15) * 128 + ot + jj] = mx;
        }
        __syncthreads();
        if (t < 128) {
            float mx = Pm[t];
            #pragma unroll
            for (int gg = 1; gg < 16; ++gg) mx = fmaxf(mx, Pm[gg * 128 + t]);
            atomicMax((unsigned int*)(gout + b * 1024 + o0 + t), __float_as_uint(mx));
        }
    } else {
        #pragma unroll
        for (int ii = 0; ii < 8; ++ii) {
            float outv[8];
            #pragma unroll
            for (int jj = 0; jj < 8; ++jj) {
                float v = acc[ii][jj] + bv[jj];
                if (RELU) v = fmaxf(v, 0.0f);
                outv[jj] = v;
            }
            float* yp = Y + (size_t)(m0 + mt + ii) * COUT + o0 + ot;
            *(float4*)yp = *(float4*)&outv[0];
            *(float4*)(yp + 4) = *(float4*)&outv[4];
        }
    }
}

// ---------------------------------------------------------------- bias3 = W_c3[:,160:] @ g + b_c3

__global__ void bias3_kernel(const float* __restrict__ g, const float* __restrict__ w_c3,
                             const float* __restrict__ b_c3, float* __restrict__ bias3) {
    __shared__ float gs[1024];
    int b = blockIdx.x >> 1;
    int o = ((blockIdx.x & 1) << 8) + threadIdx.x;
    for (int i = threadIdx.x; i < 1024; i += 256) gs[i] = g[b * 1024 + i];
    __syncthreads();
    float acc = b_c3[o];
    const float* wr = w_c3 + (size_t)o * 1184 + 160;
    for (int i = 0; i < 1024; i += 4) {
        float4 w4 = *(const float4*)(wr + i);
        acc = fmaf(w4.x, gs[i], acc);     acc = fmaf(w4.y, gs[i + 1], acc);
        acc = fmaf(w4.z, gs[i + 2], acc); acc = fmaf(w4.w, gs[i + 3], acc);
    }
    bias3[b * 512 + o] = acc;
}

// ---------------------------------------------------------------- final 128 -> 13 (no relu), output (B,13,N)

__global__ __launch_bounds__(256, 1) void c6_kernel(
    const float* __restrict__ h5, const float* __restrict__ w,
    const float* __restrict__ bias, float* __restrict__ out) {
    __shared__ float ws[13 * 128];
    __shared__ float bs[13];
    int t = threadIdx.x;
    for (int i = t; i < 13 * 128; i += 256) ws[i] = w[i];
    if (t < 13) bs[t] = bias[t];
    __syncthreads();
    int b = blockIdx.x >> 4;
    int n = ((blockIdx.x & 15) << 8) + t;
    float x[128];
    const float* xp = h5 + ((size_t)b * N_ + n) * 128;
    #pragma unroll
    for (int i = 0; i < 128; i += 4) *(float4*)&x[i] = *(const float4*)(xp + i);
    for (int o = 0; o < 13; ++o) {
        float acc = bs[o];
        #pragma unroll
        for (int i = 0; i < 128; ++i) acc = fmaf(ws[o * 128 + i], x[i], acc);
        out[((size_t)b * 13 + o) * N_ + n] = acc;
    }
}

// ---------------------------------------------------------------- launch

extern "C" void kernel_launch(void* const* d_in, const int* in_sizes, int n_in,
                              void* d_out, int out_size, void* d_ws, size_t ws_size,
                              hipStream_t stream) {
    (void)in_sizes; (void)n_in; (void)out_size; (void)ws_size;
    const float* xyz = (const float*)d_in[0];
    #define W_(j)  ((const float*)d_in[1 + 2 * (j)])
    #define Bp_(j) ((const float*)d_in[2 + 2 * (j)])

    char* ws = (char*)d_ws;
    const size_t MB = 1u << 20;
    int*   idx1  = (int*)(ws + 0 * MB);
    int*   idx2  = (int*)(ws + 2 * MB);
    float* fea1  = (float*)(ws + 4 * MB);
    float* CfPf  = (float*)(ws + 8 * MB);       // 32MB; reused later as h4
    float* fea2  = (float*)(ws + 40 * MB);
    float* h1    = (float*)(ws + 56 * MB);      // 16MB; reused later as h5
    float* sqbuf = (float*)(ws + 72 * MB);
    float* gbuf  = (float*)(ws + 72 * MB + (128u << 10));
    float* b3buf = (float*)(ws + 72 * MB + (160u << 10));
    float* wt    = (float*)(ws + 72 * MB + (176u << 10));
    float* h3    = (float*)(ws + 75 * MB);      // 64MB (also overlays knn Kbuf early)
    float* h4    = CfPf;
    float* h5    = h1;
    float* outp  = (float*)d_out;
    unsigned long long* Kbuf = (unsigned long long*)(ws + 75 * MB);  // 8.4MB, dead before h3

    float* wte1  = wt;            // 3584 (g1T, g2T @320, f1T @1344, f2T @1536, f3T @2560)
    float* wg1t2 = wt + 3584;     // 1280
    float* wtpre = wt + 4864;     // 8192
    float* bpre  = wt + 13056;    // 256
    float* wf2t  = wt + 13312;
    float* wf3t  = wt + 29696;
    float* wg2t  = wt + 46080;
    float* wc1t  = wt + 62464;
    float* wc2t  = wt + 78848;    // 131072
    float* wt3   = wt + 209920;   // 81920
    float* wt4   = wt + 291840;   // 131072
    float* wt5   = wt + 422912;   // 32768

    // one dispatch replaces 14 transposes + prep_pre + zero + sq<3>
    prep_kernel<<<1940, 256, 0, stream>>>(
        W_(0), W_(1), W_(2), W_(3), W_(4), W_(5), W_(6), W_(8), W_(9), W_(10),
        W_(11), W_(12), W_(13), W_(14), W_(7), Bp_(7), xyz, wt, gbuf, sqbuf);

    // knn1 + edgeconv1
    knn_kernel<3><<<dim3(64, 8, 2), 256, 0, stream>>>(xyz, sqbuf, Kbuf);
    knn_merge_kernel<<<128, 256, 0, stream>>>(Kbuf, idx1);
    e1_kernel<<<4096, 256, 0, stream>>>(xyz, idx1, wte1, Bp_(0), Bp_(1), Bp_(2), Bp_(3), Bp_(4), fea1);

    // knn2 + edgeconv2
    sq_kernel<32><<<128, 256, 0, stream>>>(fea1, sqbuf);
    knn_kernel<32><<<dim3(64, 8, 2), 256, 0, stream>>>(fea1, sqbuf, Kbuf);
    knn_merge_kernel<<<128, 256, 0, stream>>>(Kbuf, idx2);
    gemm_pw<0, 0, 0><<<dim3(256, 2), 256, 0, stream>>>(fea1, 32, 32, nullptr, 0, 32,
                                                       wtpre, bpre, CfPf, 256, nullptr);
    e2_kernel<<<4096, 256, 0, stream>>>(xyz, idx2, CfPf, wg1t2, wg2t, wf2t, wf3t,
                                        Bp_(5), Bp_(6), Bp_(8), Bp_(9), fea2);

    // head
    gemm_pw<1, 0, 0><<<dim3(256, 1), 256, 0, stream>>>(fea2, 128, 128, nullptr, 0, 128,
                                                       wc1t, Bp_(10), h1, 128, nullptr);
    gemm_pw<1, 0, 1><<<dim3(256, 8), 256, 0, stream>>>(h1, 128, 128, nullptr, 0, 128,
                                                       wc2t, Bp_(11), nullptr, 1024, gbuf);
    bias3_kernel<<<16, 256, 0, stream>>>(gbuf, W_(12), Bp_(12), b3buf);
    gemm_pw<1, 1, 0><<<dim3(256, 4), 256, 0, stream>>>(fea1, 32, 32, fea2, 128, 160,
                                                       wt3, b3buf, h3, 512, nullptr);
    gemm_pw<1, 0, 0><<<dim3(256, 2), 256, 0, stream>>>(h3, 512, 512, nullptr, 0, 512,
                                                       wt4, Bp_(13), h4, 256, nullptr);
    gemm_pw<1, 0, 0><<<dim3(256, 1), 256, 0, stream>>>(h4, 256, 256, nullptr, 0, 256,
                                                       wt5, Bp_(14), h5, 128, nullptr);
    c6_kernel<<<128, 256, 0, stream>>>(h5, W_(15), Bp_(15), outp);
    #undef W_
    #undef Bp_
}